// Round 10
// baseline (325.085 us; speedup 1.0000x reference)
//
#include <hip/hip_runtime.h>
#include <math.h>

typedef _Float16 f16;
typedef _Float16 f16x2 __attribute__((ext_vector_type(2)));
typedef _Float16 f16x4 __attribute__((ext_vector_type(4)));
typedef _Float16 f16x8 __attribute__((ext_vector_type(8)));
typedef float    f32x4 __attribute__((ext_vector_type(4)));

#define NB 4096
#define LT 512
#define NC 16
#define NS 32

// workspace layout (bytes)
#define WS_P0     0                     // 32 f32, softmax(init)*256
#define WS_SIG    128                   // 32 f32, sigmoid(acc)*256
#define WS_SUMSIG 256                   // 1 f32
#define WS_FWDT   512                   // 16384 f16 = 32768 B
#define WS_BWDT   (512 + 32768)
#define WS_F      (512 + 65536)         // 32*4096 f32
#define WS_G      (WS_F + 32*4096*4)

#if __has_builtin(__builtin_amdgcn_exp2f)
#define EXP2F __builtin_amdgcn_exp2f
#else
#define EXP2F exp2f
#endif

// ---------------- prep: softmaxes + fragment tables for 16x16x32 MFMA ---------
// Wave w owns source states {8w..8w+7} = 4 k-chunks (kc) of 32 k-slots.
// k-slot in chunk = 8g + j: g = 2*slsb + chalf (slsb = source-state LSB, via
// lane>>5 on the B side), c = 8*chalf + j. Two row-half MFMAs r (rows 16r..16r+15).
// A-frag convention (16x16x32): A[m = lane&15][k = 8*(lane>>4) + j].
// fwd: source = p, rows = n.   bwd: source = n, rows = p.
__global__ __launch_bounds__(512) void pdfa_prep(const float* __restrict__ tlogit,
                                                 const float* __restrict__ ilogit,
                                                 const float* __restrict__ alogit,
                                                 char* __restrict__ ws) {
    int tid = threadIdx.x;           // 512 threads = one (p,c) row each
    f16* fwdT = (f16*)(ws + WS_FWDT);
    f16* bwdT = (f16*)(ws + WS_BWDT);
    int p = tid >> 4, c = tid & 15;
    const float* row = tlogit + p * 512 + c * 32;
    float mx = row[0];
    for (int n = 1; n < 32; ++n) mx = fmaxf(mx, row[n]);
    float s = 0.f;
    for (int n = 0; n < 32; ++n) s += expf(row[n] - mx);
    float inv = 1.f / s;
    int chalf = c >> 3, j = c & 7;
    for (int n = 0; n < 32; ++n) {
        float tv = expf(row[n] - mx) * inv;
        // fwd: w=p>>3, kc=(p>>1)&3, g=2*(p&1)+chalf, r=n>>4, m=n&15
        fwdT[((((p >> 3) * 4 + ((p >> 1) & 3)) * 2 + (n >> 4)) * 64
              + 16 * (2 * (p & 1) + chalf) + (n & 15)) * 8 + j] = (f16)tv;
        // bwd: w=n>>3, kc=(n>>1)&3, g=2*(n&1)+chalf, r=p>>4, m=p&15
        bwdT[((((n >> 3) * 4 + ((n >> 1) & 3)) * 2 + (p >> 4)) * 64
              + 16 * (2 * (n & 1) + chalf) + (p & 15)) * 8 + j] = (f16)tv;
    }
    if (tid < 32) {
        float m0 = ilogit[0];
        for (int n = 1; n < 32; ++n) m0 = fmaxf(m0, ilogit[n]);
        float s0 = 0.f;
        for (int n = 0; n < 32; ++n) s0 += expf(ilogit[n] - m0);
        ((float*)(ws + WS_P0))[tid]  = 256.f * expf(ilogit[tid] - m0) / s0;
        ((float*)(ws + WS_SIG))[tid] = 256.f / (1.f + expf(-alogit[tid]));
    }
    if (tid == 0) {
        float ss = 0.f;
        for (int n = 0; n < 32; ++n) ss += 1.f / (1.f + expf(-alogit[n]));
        *(float*)(ws + WS_SUMSIG) = ss;
    }
}

// ---------------- main: 512 chains, K-split-4 (4 waves x 8 states), 2 blk/CU --
#define EC(v) ((f16)EXP2F((v) * 1.44269504089f))

#define PBUF 4608                       // 4 waves x 16 col x 72 B
#define XOFF 9216                       // 2 partial bufs
#define XB   640                        // 16 col x 40 B
// LDS total = 9216 + 1280 = 10496 B

// one time-step (phase P): 4 B-frags, 8 MFMA (4 dep-chains of 2), f16 partials
// -> LDS, every lane produces one x-hat(s+1) + issues load of t(s+2-ahead),
// barrier, read 4 partial slices + next x-hat, pk_add tree.
#define STEP(P, XRAW, TNEXT) { \
    f16x8 bf0_, bf1_, bf2_, bf3_; \
    { f16 pv_ = h32 ? pnew[1] : pnew[0]; f16x8 pb_ = {pv_,pv_,pv_,pv_,pv_,pv_,pv_,pv_}; bf0_ = pb_ * xq8; } \
    { f16 pv_ = h32 ? pnew[3] : pnew[2]; f16x8 pb_ = {pv_,pv_,pv_,pv_,pv_,pv_,pv_,pv_}; bf1_ = pb_ * xq8; } \
    { f16 pv_ = h32 ? pnew[5] : pnew[4]; f16x8 pb_ = {pv_,pv_,pv_,pv_,pv_,pv_,pv_,pv_}; bf2_ = pb_ * xq8; } \
    { f16 pv_ = h32 ? pnew[7] : pnew[6]; f16x8 pb_ = {pv_,pv_,pv_,pv_,pv_,pv_,pv_,pv_}; bf3_ = pb_ * xq8; } \
    __builtin_amdgcn_s_setprio(1); \
    f32x4 c0_ = __builtin_amdgcn_mfma_f32_16x16x32_f16(af[0][0], bf0_, z4, 0, 0, 0); \
    f32x4 c1_ = __builtin_amdgcn_mfma_f32_16x16x32_f16(af[1][0], bf0_, z4, 0, 0, 0); \
    f32x4 c2_ = __builtin_amdgcn_mfma_f32_16x16x32_f16(af[0][1], bf1_, z4, 0, 0, 0); \
    f32x4 c3_ = __builtin_amdgcn_mfma_f32_16x16x32_f16(af[1][1], bf1_, z4, 0, 0, 0); \
    c0_ = __builtin_amdgcn_mfma_f32_16x16x32_f16(af[0][2], bf2_, c0_, 0, 0, 0); \
    c1_ = __builtin_amdgcn_mfma_f32_16x16x32_f16(af[1][2], bf2_, c1_, 0, 0, 0); \
    c2_ = __builtin_amdgcn_mfma_f32_16x16x32_f16(af[0][3], bf3_, c2_, 0, 0, 0); \
    c3_ = __builtin_amdgcn_mfma_f32_16x16x32_f16(af[1][3], bf3_, c3_, 0, 0, 0); \
    __builtin_amdgcn_s_setprio(0); \
    f32x4 r0_ = c0_ + c2_, r1_ = c1_ + c3_; \
    char* wp_ = lds + (P) * PBUF + w * 1152 + col * 72 + 8 * h4; \
    *(f16x4*)(wp_)      = f16x4{(f16)r0_[0], (f16)r0_[1], (f16)r0_[2], (f16)r0_[3]}; \
    *(f16x4*)(wp_ + 32) = f16x4{(f16)r1_[0], (f16)r1_[1], (f16)r1_[2], (f16)r1_[3]}; \
    *(f16*)(xw + (((P)^1)) * XB) = EC(XRAW); \
    XRAW = xg[(size_t)(TNEXT) * NC]; \
    __syncthreads(); \
    const char* rp_ = lds + (P) * PBUF + col * 72 + 16 * w; \
    f16x8 q0_ = *(const f16x8*)(rp_); \
    f16x8 q1_ = *(const f16x8*)(rp_ + 1152); \
    f16x8 q2_ = *(const f16x8*)(rp_ + 2304); \
    f16x8 q3_ = *(const f16x8*)(rp_ + 3456); \
    xq8 = *(const f16x8*)(xr + (((P)^1)) * XB); \
    pnew = (q0_ + q1_) + (q2_ + q3_); }

__global__ __launch_bounds__(256, 2) void pdfa_main(const float* __restrict__ login,
                                                    char* __restrict__ ws) {
    __shared__ __align__(16) char lds[2 * PBUF + 2 * XB];
    const int tid  = threadIdx.x;
    const int w    = tid >> 6;              // 0..3: wave = source-state group (8w..8w+7)
    const int lane = tid & 63;
    const int col  = lane & 15;             // batch column within 16-wide tile
    const int h4   = lane >> 4;             // 0..3: D row group
    const int chalf = h4 & 1;
    const int h32  = lane >> 5;             // source-state LSB on B side
    const int bid  = blockIdx.x;
    const int dir  = bid & 1;               // 0 = fwd (t 0..255), 1 = bwd (t 511..256)
    const int b0   = (bid >> 1) << 4;

    // this wave's 8 A-frags [r][kc], 8 x 16B = 32 VGPRs
    const char* tblb = ws + (dir ? WS_BWDT : WS_FWDT);
    f16x8 af[2][4];
#pragma unroll
    for (int r = 0; r < 2; ++r)
#pragma unroll
        for (int kc = 0; kc < 4; ++kc)
            af[r][kc] = *(const f16x8*)(tblb + (((w * 4 + kc) * 2 + r) * 64 + lane) * 16);

    // running state: own 8 source states (8w..8w+7), value for column `col`
    const float* initv = (const float*)(ws + (dir ? WS_SIG : WS_P0));
    f16x8 pnew;
#pragma unroll
    for (int j = 0; j < 8; ++j) pnew[j] = (f16)initv[8 * w + j];

    // x-hat producer: every thread produces one (colv, cv) value per step
    const int colv = (tid >> 4) & 15, cv = tid & 15;
    const float* xg = login + (size_t)(b0 + colv) * (LT * NC) + cv;
    char* xw = lds + XOFF + colv * 40 + cv * 2;
    const char* xr = lds + XOFF + col * 40 + chalf * 16;

    const f32x4 z4{};
    f16x8 xq8;
    float xrA, xrB;

#define TT(S) (dir ? (511 - (S)) : (S))
    xrA = xg[(size_t)TT(0) * NC];
    xrB = xg[(size_t)TT(1) * NC];
    *(f16*)(xw) = EC(xrA);                  // xbuf0 = x-hat(t0)
    xrA = xg[(size_t)TT(2) * NC];           // A now prefetches t2
    __syncthreads();
    xq8 = *(const f16x8*)(xr);

    for (int s = 0; s < 256; s += 2) {
        STEP(0, xrB, TT(s + 3))             // uses x-hat(s); produces x-hat(s+1); loads t(s+3)
        STEP(1, xrA, TT(s + 4))             // uses x-hat(s+1); produces x-hat(s+2); loads t(s+4)
    }
#undef TT

    // final p (states 8w..8w+7, col) -> f or g, laid out [state][b]
    if (h4 == 0) {
        float* outv = (float*)(ws + (dir ? WS_G : WS_F));
#pragma unroll
        for (int j = 0; j < 8; ++j)
            outv[(size_t)(8 * w + j) * NB + b0 + col] = (float)pnew[j];
    }
}

// ---------------- combine: out[b] = log( f.g / 65536 + 1e-20*sum(sigma) ) ------
__global__ __launch_bounds__(256) void pdfa_combine(const char* __restrict__ ws,
                                                    float* __restrict__ out) {
    int b = blockIdx.x * 256 + threadIdx.x;
    const float* f = (const float*)(ws + WS_F);
    const float* g = (const float*)(ws + WS_G);
    float ss = *(const float*)(ws + WS_SUMSIG);
    float dot = 0.f;
#pragma unroll
    for (int s2 = 0; s2 < 32; ++s2)
        dot = fmaf(f[s2 * NB + b], g[s2 * NB + b], dot);
    out[b] = logf(dot * (1.f / 65536.f) + 1e-20f * ss);
}

extern "C" void kernel_launch(void* const* d_in, const int* in_sizes, int n_in,
                              void* d_out, int out_size, void* d_ws, size_t ws_size,
                              hipStream_t stream) {
    const float* login = (const float*)d_in[0];
    const float* ilog  = (const float*)d_in[1];
    const float* tlog  = (const float*)d_in[2];
    const float* alog  = (const float*)d_in[3];
    char* ws = (char*)d_ws;

    pdfa_prep<<<1, 512, 0, stream>>>(tlog, ilog, alog, ws);
    pdfa_main<<<512, 256, 0, stream>>>(login, ws);
    pdfa_combine<<<NB / 256, 256, 0, stream>>>(ws, (float*)d_out);
}

// Round 11
// 253.190 us; speedup vs baseline: 1.2840x; 1.2840x over previous
//
#include <hip/hip_runtime.h>
#include <math.h>

typedef _Float16 f16;
typedef _Float16 f16x2 __attribute__((ext_vector_type(2)));
typedef _Float16 f16x4 __attribute__((ext_vector_type(4)));
typedef _Float16 f16x8 __attribute__((ext_vector_type(8)));
typedef float    f32x4 __attribute__((ext_vector_type(4)));

#define NB 4096
#define LT 512
#define NC 16
#define NS 32

// workspace layout (bytes)
#define WS_P0     0                     // 32 f32, softmax(init)*256
#define WS_SIG    128                   // 32 f32, sigmoid(acc)*256
#define WS_SUMSIG 256                   // 1 f32
#define WS_FWDT   512                   // 16384 f16 = 32768 B
#define WS_BWDT   (512 + 32768)
#define WS_F      (512 + 65536)         // 32*4096 f32
#define WS_G      (WS_F + 32*4096*4)

#if __has_builtin(__builtin_amdgcn_exp2f)
#define EXP2F __builtin_amdgcn_exp2f
#else
#define EXP2F exp2f
#endif

// ---------------- prep: softmaxes + fragment tables for 16x16x32 MFMA ---------
// Wave w owns source states {4w..4w+3} = 2 k-chunks (kc) of 32 k-slots.
// k-slot in chunk = 8g + j: g = 2*slsb + chalf (slsb via lane>>5 on B side),
// c = 8*chalf + j. Two row-half MFMAs r (rows 16r..16r+15).
// A-frag convention (16x16x32): A[m = lane&15][k = 8*(lane>>4) + j].
// fwd: source = p, rows = n.   bwd: source = n, rows = p.
__global__ __launch_bounds__(512) void pdfa_prep(const float* __restrict__ tlogit,
                                                 const float* __restrict__ ilogit,
                                                 const float* __restrict__ alogit,
                                                 char* __restrict__ ws) {
    int tid = threadIdx.x;           // 512 threads = one (p,c) row each
    f16* fwdT = (f16*)(ws + WS_FWDT);
    f16* bwdT = (f16*)(ws + WS_BWDT);
    int p = tid >> 4, c = tid & 15;
    const float* row = tlogit + p * 512 + c * 32;
    float mx = row[0];
    for (int n = 1; n < 32; ++n) mx = fmaxf(mx, row[n]);
    float s = 0.f;
    for (int n = 0; n < 32; ++n) s += expf(row[n] - mx);
    float inv = 1.f / s;
    int chalf = c >> 3, j = c & 7;
    for (int n = 0; n < 32; ++n) {
        float tv = expf(row[n] - mx) * inv;
        // fwd: w=p>>2, kc=(p>>1)&1, g=2*(p&1)+chalf, r=n>>4, m=n&15
        fwdT[((((p >> 2) * 2 + ((p >> 1) & 1)) * 2 + (n >> 4)) * 64
              + 16 * (2 * (p & 1) + chalf) + (n & 15)) * 8 + j] = (f16)tv;
        // bwd: w=n>>2, kc=(n>>1)&1, g=2*(n&1)+chalf, r=p>>4, m=p&15
        bwdT[((((n >> 2) * 2 + ((n >> 1) & 1)) * 2 + (p >> 4)) * 64
              + 16 * (2 * (n & 1) + chalf) + (p & 15)) * 8 + j] = (f16)tv;
    }
    if (tid < 32) {
        float m0 = ilogit[0];
        for (int n = 1; n < 32; ++n) m0 = fmaxf(m0, ilogit[n]);
        float s0 = 0.f;
        for (int n = 0; n < 32; ++n) s0 += expf(ilogit[n] - m0);
        ((float*)(ws + WS_P0))[tid]  = 256.f * expf(ilogit[tid] - m0) / s0;
        ((float*)(ws + WS_SIG))[tid] = 256.f / (1.f + expf(-alogit[tid]));
    }
    if (tid == 0) {
        float ss = 0.f;
        for (int n = 0; n < 32; ++n) ss += 1.f / (1.f + expf(-alogit[n]));
        *(float*)(ws + WS_SUMSIG) = ss;
    }
}

// ---------------- main: fused fwd+bwd per block, 256 blocks, 8 waves ----------
#define EC(v) ((f16)EXP2F((v) * 1.44269504089f))

#define PBUF 9216                       // 8 waves x 16 col x 72 B
#define XOFF (4 * PBUF)                 // partials: [phase 2][dir 2][PBUF]
#define XB   640                        // 16 col x 40 B
// x-hat: [phase 2][dir 2][XB]; LDS total = 36864 + 2560 = 39424 B

// one B-frag from a state pair + shared x-hat vector
#define BBUILD(BF, PN, XQ, LO, HI) { \
    f16 pv_ = h32 ? PN[HI] : PN[LO]; \
    f16x8 pb_ = {pv_, pv_, pv_, pv_, pv_, pv_, pv_, pv_}; \
    BF = pb_ * XQ; }

// one fused time-step (phase P): both dirs' 8 MFMA (4 dep chains, distance 4),
// f16 partials -> LDS, one x-hat produced per thread (own dir), barrier,
// read 8 partials per dir + next x-hat, pk_add trees.
#define STEP(P, XRAW, TNEXT) { \
    f16x8 bf0f_, bf1f_, bf0b_, bf1b_; \
    BBUILD(bf0f_, pnf, xq8f, 0, 1)  BBUILD(bf1f_, pnf, xq8f, 2, 3) \
    BBUILD(bf0b_, pnb, xq8b, 0, 1)  BBUILD(bf1b_, pnb, xq8b, 2, 3) \
    __builtin_amdgcn_s_setprio(1); \
    f32x4 c0f_ = __builtin_amdgcn_mfma_f32_16x16x32_f16(aff[0][0], bf0f_, z4, 0, 0, 0); \
    f32x4 c1f_ = __builtin_amdgcn_mfma_f32_16x16x32_f16(aff[1][0], bf0f_, z4, 0, 0, 0); \
    f32x4 c0b_ = __builtin_amdgcn_mfma_f32_16x16x32_f16(afb[0][0], bf0b_, z4, 0, 0, 0); \
    f32x4 c1b_ = __builtin_amdgcn_mfma_f32_16x16x32_f16(afb[1][0], bf0b_, z4, 0, 0, 0); \
    c0f_ = __builtin_amdgcn_mfma_f32_16x16x32_f16(aff[0][1], bf1f_, c0f_, 0, 0, 0); \
    c1f_ = __builtin_amdgcn_mfma_f32_16x16x32_f16(aff[1][1], bf1f_, c1f_, 0, 0, 0); \
    c0b_ = __builtin_amdgcn_mfma_f32_16x16x32_f16(afb[0][1], bf1b_, c0b_, 0, 0, 0); \
    c1b_ = __builtin_amdgcn_mfma_f32_16x16x32_f16(afb[1][1], bf1b_, c1b_, 0, 0, 0); \
    __builtin_amdgcn_s_setprio(0); \
    { char* wf_ = lds + (P) * 2 * PBUF + w * 1152 + col * 72 + 8 * h4; \
      *(f16x4*)(wf_)      = f16x4{(f16)c0f_[0], (f16)c0f_[1], (f16)c0f_[2], (f16)c0f_[3]}; \
      *(f16x4*)(wf_ + 32) = f16x4{(f16)c1f_[0], (f16)c1f_[1], (f16)c1f_[2], (f16)c1f_[3]}; \
      char* wb_ = wf_ + PBUF; \
      *(f16x4*)(wb_)      = f16x4{(f16)c0b_[0], (f16)c0b_[1], (f16)c0b_[2], (f16)c0b_[3]}; \
      *(f16x4*)(wb_ + 32) = f16x4{(f16)c1b_[0], (f16)c1b_[1], (f16)c1b_[2], (f16)c1b_[3]}; } \
    *(f16*)(xw + (((P)^1)) * 2 * XB) = EC(XRAW); \
    XRAW = xg[(size_t)(TNEXT) * NC]; \
    __syncthreads(); \
    { const char* rf_ = lds + (P) * 2 * PBUF + col * 72 + 8 * w; \
      f16x4 q0_ = *(const f16x4*)(rf_); \
      f16x4 q1_ = *(const f16x4*)(rf_ + 1152); \
      f16x4 q2_ = *(const f16x4*)(rf_ + 2304); \
      f16x4 q3_ = *(const f16x4*)(rf_ + 3456); \
      f16x4 q4_ = *(const f16x4*)(rf_ + 4608); \
      f16x4 q5_ = *(const f16x4*)(rf_ + 5760); \
      f16x4 q6_ = *(const f16x4*)(rf_ + 6912); \
      f16x4 q7_ = *(const f16x4*)(rf_ + 8064); \
      pnf = ((q0_ + q1_) + (q2_ + q3_)) + ((q4_ + q5_) + (q6_ + q7_)); \
      const char* rb_ = rf_ + PBUF; \
      f16x4 u0_ = *(const f16x4*)(rb_); \
      f16x4 u1_ = *(const f16x4*)(rb_ + 1152); \
      f16x4 u2_ = *(const f16x4*)(rb_ + 2304); \
      f16x4 u3_ = *(const f16x4*)(rb_ + 3456); \
      f16x4 u4_ = *(const f16x4*)(rb_ + 4608); \
      f16x4 u5_ = *(const f16x4*)(rb_ + 5760); \
      f16x4 u6_ = *(const f16x4*)(rb_ + 6912); \
      f16x4 u7_ = *(const f16x4*)(rb_ + 8064); \
      pnb = ((u0_ + u1_) + (u2_ + u3_)) + ((u4_ + u5_) + (u6_ + u7_)); } \
    xq8f = *(const f16x8*)(xrf + (((P)^1)) * 2 * XB); \
    xq8b = *(const f16x8*)(xrb + (((P)^1)) * 2 * XB); }

__global__ __launch_bounds__(512, 1) void pdfa_main(const float* __restrict__ login,
                                                    char* __restrict__ ws) {
    __shared__ __align__(16) char lds[4 * PBUF + 4 * XB];
    const int tid  = threadIdx.x;
    const int w    = tid >> 6;              // 0..7: wave = source-state group (4w..4w+3)
    const int lane = tid & 63;
    const int col  = lane & 15;             // batch column within 16-wide tile
    const int h4   = lane >> 4;             // 0..3: D row group / B k-quarter
    const int chalf = h4 & 1;
    const int h32  = lane >> 5;             // source-state LSB on B side
    const int b0   = blockIdx.x << 4;

    // A-frags for BOTH dirs: [r][kc], 4+4 x 16B = 32 VGPRs
    const char* tf = ws + WS_FWDT;
    const char* tb = ws + WS_BWDT;
    f16x8 aff[2][2], afb[2][2];
#pragma unroll
    for (int r = 0; r < 2; ++r)
#pragma unroll
        for (int kc = 0; kc < 2; ++kc) {
            aff[r][kc] = *(const f16x8*)(tf + (((w * 2 + kc) * 2 + r) * 64 + lane) * 16);
            afb[r][kc] = *(const f16x8*)(tb + (((w * 2 + kc) * 2 + r) * 64 + lane) * 16);
        }

    // running states: own 4 source states (4w..4w+3), both dirs
    const float* p0v = (const float*)(ws + WS_P0);
    const float* sgv = (const float*)(ws + WS_SIG);
    f16x4 pnf, pnb;
#pragma unroll
    for (int j = 0; j < 4; ++j) { pnf[j] = (f16)p0v[4 * w + j]; pnb[j] = (f16)sgv[4 * w + j]; }

    // x-hat producer: waves 0-3 -> fwd stream, waves 4-7 -> bwd stream
    const int pdir = tid >> 8;              // 0 = fwd, 1 = bwd
    const int colv = (tid >> 4) & 15, cv = tid & 15;
    const float* xg = login + (size_t)(b0 + colv) * (LT * NC) + cv;
    char* xw = lds + XOFF + pdir * XB + colv * 40 + cv * 2;
    const char* xrf = lds + XOFF + col * 40 + chalf * 16;
    const char* xrb = xrf + XB;

    const f32x4 z4{};
    f16x8 xq8f, xq8b;
    float xrA, xrB;

#define TTD(S) (pdir ? (511 - (S)) : (S))
    xrA = xg[(size_t)TTD(0) * NC];
    xrB = xg[(size_t)TTD(1) * NC];
    *(f16*)(xw) = EC(xrA);                  // phase-0 x-hat = t0 (own dir)
    xrA = xg[(size_t)TTD(2) * NC];          // A-reg now prefetches t2
    __syncthreads();
    xq8f = *(const f16x8*)(xrf);
    xq8b = *(const f16x8*)(xrb);

    for (int s = 0; s < 256; s += 2) {
        STEP(0, xrB, TTD(s + 3))            // uses x-hat(s); produces x-hat(s+1); loads t(s+3)
        STEP(1, xrA, TTD(s + 4))            // uses x-hat(s+1); produces x-hat(s+2); loads t(s+4)
    }
#undef TTD

    // final p (states 4w..4w+3, col) -> f and g, laid out [state][b]
    if (lane < 16) {
        float* outf = (float*)(ws + WS_F);
        float* outg = (float*)(ws + WS_G);
#pragma unroll
        for (int j = 0; j < 4; ++j) {
            outf[(size_t)(4 * w + j) * NB + b0 + col] = (float)pnf[j];
            outg[(size_t)(4 * w + j) * NB + b0 + col] = (float)pnb[j];
        }
    }
}

// ---------------- combine: out[b] = log( f.g / 65536 + 1e-20*sum(sigma) ) ------
__global__ __launch_bounds__(256) void pdfa_combine(const char* __restrict__ ws,
                                                    float* __restrict__ out) {
    int b = blockIdx.x * 256 + threadIdx.x;
    const float* f = (const float*)(ws + WS_F);
    const float* g = (const float*)(ws + WS_G);
    float ss = *(const float*)(ws + WS_SUMSIG);
    float dot = 0.f;
#pragma unroll
    for (int s2 = 0; s2 < 32; ++s2)
        dot = fmaf(f[s2 * NB + b], g[s2 * NB + b], dot);
    out[b] = logf(dot * (1.f / 65536.f) + 1e-20f * ss);
}

extern "C" void kernel_launch(void* const* d_in, const int* in_sizes, int n_in,
                              void* d_out, int out_size, void* d_ws, size_t ws_size,
                              hipStream_t stream) {
    const float* login = (const float*)d_in[0];
    const float* ilog  = (const float*)d_in[1];
    const float* tlog  = (const float*)d_in[2];
    const float* alog  = (const float*)d_in[3];
    char* ws = (char*)d_ws;

    pdfa_prep<<<1, 512, 0, stream>>>(tlog, ilog, alog, ws);
    pdfa_main<<<256, 512, 0, stream>>>(login, ws);
    pdfa_combine<<<NB / 256, 256, 0, stream>>>(ws, (float*)d_out);
}

// Round 12
// 175.898 us; speedup vs baseline: 1.8481x; 1.4394x over previous
//
#include <hip/hip_runtime.h>
#include <math.h>

typedef _Float16 f16;
typedef _Float16 f16x2 __attribute__((ext_vector_type(2)));
typedef _Float16 f16x4 __attribute__((ext_vector_type(4)));
typedef _Float16 f16x8 __attribute__((ext_vector_type(8)));
typedef float    f32x4 __attribute__((ext_vector_type(4)));

#define NB 4096
#define LT 512
#define NC 16
#define NS 32

// workspace layout (bytes)
#define WS_P0     0                     // 32 f32, softmax(init)*256
#define WS_SIG    128                   // 32 f32, sigmoid(acc)*256
#define WS_SUMSIG 256                   // 1 f32
#define WS_FWDT   512                   // 16384 f16 = 32768 B
#define WS_BWDT   (512 + 32768)
#define WS_F      (512 + 65536)         // 32*4096 f32
#define WS_G      (WS_F + 32*4096*4)

#if __has_builtin(__builtin_amdgcn_exp2f)
#define EXP2F __builtin_amdgcn_exp2f
#else
#define EXP2F exp2f
#endif

// ---------------- prep: softmaxes + fragment tables (exchange-free layout) ----
// K=512 flattening: k-slot (chunk kc, octet q, elem j) <-> source state
// st(q,j) = 4q + (j&3) + 16*(j>>2), symbol c = kc.  (st is exactly the state
// set lane (q,*) holds in the 16x16x32 D-layout: rows 4q..4q+3 of each half.)
// A-frag [kc][r] at lane (q,m): elem j = T[st(q,j)][kc][16r+m]   (fwd: dest=n)
// bwd swaps roles: dest = p (rows), source = n:   elem j = T[16r+m][kc][st(q,j)]
__global__ __launch_bounds__(512) void pdfa_prep(const float* __restrict__ tlogit,
                                                 const float* __restrict__ ilogit,
                                                 const float* __restrict__ alogit,
                                                 char* __restrict__ ws) {
    int tid = threadIdx.x;           // 512 threads = one (p,c) row each
    f16* fwdT = (f16*)(ws + WS_FWDT);
    f16* bwdT = (f16*)(ws + WS_BWDT);
    int p = tid >> 4, c = tid & 15;
    const float* row = tlogit + p * 512 + c * 32;
    float mx = row[0];
    for (int n = 1; n < 32; ++n) mx = fmaxf(mx, row[n]);
    float s = 0.f;
    for (int n = 0; n < 32; ++n) s += expf(row[n] - mx);
    float inv = 1.f / s;
    for (int n = 0; n < 32; ++n) {
        float tv = expf(row[n] - mx) * inv;
        // fwd: source p -> (q,j); dest n -> (r,m); chunk = c
        {
            int q = (p & 15) >> 2, j = (p & 3) + 4 * (p >> 4);
            int r = n >> 4, m = n & 15;
            fwdT[((c * 2 + r) * 64 + 16 * q + m) * 8 + j] = (f16)tv;
        }
        // bwd: source n -> (q,j); dest p -> (r,m); chunk = c
        {
            int q = (n & 15) >> 2, j = (n & 3) + 4 * (n >> 4);
            int r = p >> 4, m = p & 15;
            bwdT[((c * 2 + r) * 64 + 16 * q + m) * 8 + j] = (f16)tv;
        }
    }
    if (tid < 32) {
        float m0 = ilogit[0];
        for (int n = 1; n < 32; ++n) m0 = fmaxf(m0, ilogit[n]);
        float s0 = 0.f;
        for (int n = 0; n < 32; ++n) s0 += expf(ilogit[n] - m0);
        ((float*)(ws + WS_P0))[tid]  = 256.f * expf(ilogit[tid] - m0) / s0;
        ((float*)(ws + WS_SIG))[tid] = 256.f / (1.f + expf(-alogit[tid]));
    }
    if (tid == 0) {
        float ss = 0.f;
        for (int n = 0; n < 32; ++n) ss += 1.f / (1.f + expf(-alogit[n]));
        *(float*)(ws + WS_SUMSIG) = ss;
    }
}

// ---------------- main: 512 single-wave chains, no LDS, no barriers ----------
#define EC(v) ((f16)EXP2F((v) * 1.44269504089f))

__global__ __launch_bounds__(64, 1) void pdfa_main(const float* __restrict__ login,
                                                   char* __restrict__ ws) {
    const int lane = threadIdx.x;
    const int q    = lane >> 4;             // octet / D-row group
    const int col  = lane & 15;             // batch column within 16-wide tile
    const int bid  = blockIdx.x;
    const int dir  = bid & 1;               // 0 = fwd (t 0..255), 1 = bwd (t 511..256)
    const int b0   = (bid >> 1) << 4;

    // full A-table for this dir: 32 frags x 16 B = 128 VGPRs
    const char* tblb = ws + (dir ? WS_BWDT : WS_FWDT);
    f16x8 af[16][2];
#pragma unroll
    for (int kc = 0; kc < 16; ++kc)
#pragma unroll
        for (int r = 0; r < 2; ++r)
            af[kc][r] = *(const f16x8*)(tblb + ((kc * 2 + r) * 64 + lane) * 16);

    // running state held as this lane's 8 D-output states:
    // pvec[j] = p[4q + (j&3) + 16*(j>>2)]
    const float* initv = (const float*)(ws + (dir ? WS_SIG : WS_P0));
    f32x4 pr0, pr1;
#pragma unroll
    for (int j = 0; j < 4; ++j) { pr0[j] = initv[4 * q + j]; pr1[j] = initv[16 + 4 * q + j]; }
    f16x8 pvec = {(f16)pr0[0], (f16)pr0[1], (f16)pr0[2], (f16)pr0[3],
                  (f16)pr1[0], (f16)pr1[1], (f16)pr1[2], (f16)pr1[3]};

    // raw x for this lane's column (4 lanes/col redundant -> HW-merged loads)
    const float* xg = login + (size_t)(b0 + col) * (LT * NC);
    const f32x4 z4{};
    f32x4 rn[4];
    f16x8 xq0, xq1;

#define TT(S)  (dir ? (511 - (S)) : (S))
#define TTC(S) TT((((S) > 511) ? 511 : (S)))
    {   // prologue: x-hat(t0) -> xq, raw(t1) -> rn
        const f32x4* sp = (const f32x4*)(xg + (size_t)TT(0) * NC);
        f32x4 r0 = sp[0], r1 = sp[1], r2 = sp[2], r3 = sp[3];
        xq0 = f16x8{EC(r0[0]), EC(r0[1]), EC(r0[2]), EC(r0[3]),
                    EC(r1[0]), EC(r1[1]), EC(r1[2]), EC(r1[3])};
        xq1 = f16x8{EC(r2[0]), EC(r2[1]), EC(r2[2]), EC(r2[3]),
                    EC(r3[0]), EC(r3[1]), EC(r3[2]), EC(r3[3])};
        const f32x4* sp1 = (const f32x4*)(xg + (size_t)TT(1) * NC);
        rn[0] = sp1[0]; rn[1] = sp1[1]; rn[2] = sp1[2]; rn[3] = sp1[3];
    }

    for (int s = 0; s < 256; ++s) {
        // 32 MFMAs: 8 acc chains (4 per row-half), dep distance = 8 issues
        f32x4 a0[4], a1[4];
        __builtin_amdgcn_s_setprio(1);
#pragma unroll
        for (int kc = 0; kc < 16; ++kc) {
            f16 xs = (kc < 8) ? xq0[kc & 7] : xq1[kc & 7];
            f16x8 bs = {xs, xs, xs, xs, xs, xs, xs, xs};
            f16x8 bf = pvec * bs;
            if (kc < 4) {
                a0[kc & 3] = __builtin_amdgcn_mfma_f32_16x16x32_f16(af[kc][0], bf, z4, 0, 0, 0);
                a1[kc & 3] = __builtin_amdgcn_mfma_f32_16x16x32_f16(af[kc][1], bf, z4, 0, 0, 0);
            } else {
                a0[kc & 3] = __builtin_amdgcn_mfma_f32_16x16x32_f16(af[kc][0], bf, a0[kc & 3], 0, 0, 0);
                a1[kc & 3] = __builtin_amdgcn_mfma_f32_16x16x32_f16(af[kc][1], bf, a1[kc & 3], 0, 0, 0);
            }
        }
        __builtin_amdgcn_s_setprio(0);

        // off-critical-path: convert raw(t=s+1) -> x-hat, prefetch raw(t=s+2)
        f16x8 xn0 = f16x8{EC(rn[0][0]), EC(rn[0][1]), EC(rn[0][2]), EC(rn[0][3]),
                          EC(rn[1][0]), EC(rn[1][1]), EC(rn[1][2]), EC(rn[1][3])};
        f16x8 xn1 = f16x8{EC(rn[2][0]), EC(rn[2][1]), EC(rn[2][2]), EC(rn[2][3]),
                          EC(rn[3][0]), EC(rn[3][1]), EC(rn[3][2]), EC(rn[3][3])};
        {
            const f32x4* sp = (const f32x4*)(xg + (size_t)TTC(s + 2) * NC);
            rn[0] = sp[0]; rn[1] = sp[1]; rn[2] = sp[2]; rn[3] = sp[3];
        }

        // reduce 8 accs -> new state, repack to f16
        pr0 = (a0[0] + a0[1]) + (a0[2] + a0[3]);
        pr1 = (a1[0] + a1[1]) + (a1[2] + a1[3]);
        pvec = f16x8{(f16)pr0[0], (f16)pr0[1], (f16)pr0[2], (f16)pr0[3],
                     (f16)pr1[0], (f16)pr1[1], (f16)pr1[2], (f16)pr1[3]};
        xq0 = xn0; xq1 = xn1;
    }
#undef TT
#undef TTC

    // final p -> f or g, laid out [state][b]; lane holds states 4q+j / 16+4q+j
    float* outv = (float*)(ws + (dir ? WS_G : WS_F));
#pragma unroll
    for (int j = 0; j < 4; ++j) {
        outv[(size_t)(4 * q + j) * NB + b0 + col]      = pr0[j];
        outv[(size_t)(16 + 4 * q + j) * NB + b0 + col] = pr1[j];
    }
}

// ---------------- combine: out[b] = log( f.g / 65536 + 1e-20*sum(sigma) ) ------
__global__ __launch_bounds__(256) void pdfa_combine(const char* __restrict__ ws,
                                                    float* __restrict__ out) {
    int b = blockIdx.x * 256 + threadIdx.x;
    const float* f = (const float*)(ws + WS_F);
    const float* g = (const float*)(ws + WS_G);
    float ss = *(const float*)(ws + WS_SUMSIG);
    float dot = 0.f;
#pragma unroll
    for (int s2 = 0; s2 < 32; ++s2)
        dot = fmaf(f[s2 * NB + b], g[s2 * NB + b], dot);
    out[b] = logf(dot * (1.f / 65536.f) + 1e-20f * ss);
}

extern "C" void kernel_launch(void* const* d_in, const int* in_sizes, int n_in,
                              void* d_out, int out_size, void* d_ws, size_t ws_size,
                              hipStream_t stream) {
    const float* login = (const float*)d_in[0];
    const float* ilog  = (const float*)d_in[1];
    const float* tlog  = (const float*)d_in[2];
    const float* alog  = (const float*)d_in[3];
    char* ws = (char*)d_ws;

    pdfa_prep<<<1, 512, 0, stream>>>(tlog, ilog, alog, ws);
    pdfa_main<<<512, 64, 0, stream>>>(login, ws);
    pdfa_combine<<<NB / 256, 256, 0, stream>>>(ws, (float*)d_out);
}